// Round 3
// baseline (26663.351 us; speedup 1.0000x reference)
//
#include <hip/hip_runtime.h>
#include <cmath>

#define BM   256   // rows per block
#define NH   128   // hidden chunk width
#define BK   16    // K slice
#define NE   16
#define DIN  256
#define DHID 512
#define XSTR 256   // x_sl row stride (no pad: writes stride-1, reads broadcast/2-way)
#define WOFF (BK * XSTR)   // w_sl float offset within smem

template<int CTRL>
__device__ __forceinline__ float dpp_xor_add(float v) {
    int s = __builtin_amdgcn_update_dpp(0, __float_as_int(v), CTRL, 0xF, 0xF, true);
    return v + __int_as_float(s);
}
template<int OFF>
__device__ __forceinline__ float swz_xor_add(float v) {
    int s = __builtin_amdgcn_ds_swizzle(__float_as_int(v), OFF);
    return v + __int_as_float(s);
}

__device__ __forceinline__ void load_lds16(const float* g, float* l) {
    __builtin_amdgcn_global_load_lds(
        (const __attribute__((address_space(1))) void*)g,
        (__attribute__((address_space(3))) void*)l,
        16, 0, 0);
}

__global__ __launch_bounds__(256, 4)
void moe_router(const float* __restrict__ x,
                const float* __restrict__ w1,
                const float* __restrict__ b1,
                const float* __restrict__ w2,
                const float* __restrict__ b2,
                float* __restrict__ out)
{
    // x_sl: [BK][XSTR] transposed x slice; w_sl: [BK][NH] linear (global_load_lds dest)
    // epilogue overlay l_lds: [BM][NE+1] = 4352 floats <= 6144
    __shared__ __align__(16) float smem[BK * XSTR + BK * NH];
    float* x_sl  = smem;
    float* w_sl  = smem + WOFF;
    float* l_lds = smem;

    const int t    = threadIdx.x;
    const int tc   = t & 15;    // column group / owned expert (pinned by reduction tree)
    const int tr   = t >> 4;    // row group (rows tr*16 .. tr*16+15)
    const int lane = t & 63;
    const int wv   = t >> 6;    // wave id 0..3
    const long long row0 = (long long)blockIdx.x * BM;

    float logits[16];
#pragma unroll
    for (int i = 0; i < 16; ++i) logits[i] = 0.f;

    for (int ch = 0; ch < DHID / NH; ++ch) {
        const int nh0 = ch * NH;
        float acc[16][8];
#pragma unroll
        for (int i = 0; i < 16; ++i)
#pragma unroll
            for (int j = 0; j < 8; ++j) acc[i][j] = 0.f;

        for (int ks = 0; ks < DIN / BK; ++ks) {
            const int k0 = ks * BK;

            // ---- stage w1 slice via global_load_lds (wave-uniform LDS base) ----
            // wave wv, rep u covers w_sl float range [512*wv + 256*u, +256):
            //   lane -> row wk = 4*wv + 2*u + (lane>>5), cols 4*(lane&31)..+3
            {
                const float* s0 = w1 + (long long)(k0 + 4 * wv + (lane >> 5)) * DHID
                                     + nh0 + 4 * (lane & 31);
                load_lds16(s0,             w_sl + 512 * wv + 256 * 0);
                load_lds16(s0 + 2 * DHID,  w_sl + 512 * wv + 256 * 1);
            }
            // ---- stage x slice (transposed): thread t owns row t, 16 k's ----
            {
                const float* xg = x + (row0 + t) * DIN + k0;
#pragma unroll
                for (int u = 0; u < 4; ++u) {
                    float4 v = ((const float4*)xg)[u];
                    const int kk = u * 4;
                    x_sl[(kk + 0) * XSTR + t] = v.x;
                    x_sl[(kk + 1) * XSTR + t] = v.y;
                    x_sl[(kk + 2) * XSTR + t] = v.z;
                    x_sl[(kk + 3) * XSTR + t] = v.w;
                }
            }
            __syncthreads();

            // ---- 256x128x16 fp32 register-tile step: 16x8 per thread ----
#pragma unroll 4
            for (int k = 0; k < BK; ++k) {
                float4 xa = *(const float4*)&x_sl[k * XSTR + tr * 16];
                float4 xb = *(const float4*)&x_sl[k * XSTR + tr * 16 + 4];
                float4 xc = *(const float4*)&x_sl[k * XSTR + tr * 16 + 8];
                float4 xd = *(const float4*)&x_sl[k * XSTR + tr * 16 + 12];
                float4 wa = *(const float4*)&w_sl[k * NH + tc * 4];
                float4 wb = *(const float4*)&w_sl[k * NH + 64 + tc * 4];
                float xr[16] = {xa.x, xa.y, xa.z, xa.w, xb.x, xb.y, xb.z, xb.w,
                                xc.x, xc.y, xc.z, xc.w, xd.x, xd.y, xd.z, xd.w};
                float wc[8]  = {wa.x, wa.y, wa.z, wa.w, wb.x, wb.y, wb.z, wb.w};
#pragma unroll
                for (int i = 0; i < 16; ++i)
#pragma unroll
                    for (int j = 0; j < 8; ++j)
                        acc[i][j] = fmaf(xr[i], wc[j], acc[i][j]);
            }
            __syncthreads();
        }

        // ---- bias + relu ----
#pragma unroll
        for (int j = 0; j < 8; ++j) {
            const int cj = tc * 4 + (j & 3) + ((j >> 2) << 6);
            const float bj = b1[nh0 + cj];
#pragma unroll
            for (int i = 0; i < 16; ++i)
                acc[i][j] = fmaxf(acc[i][j] + bj, 0.f);
        }

        // ---- fused layer 2 (register-only; DPP xor1/xor2 + swizzle xor4/xor8) ----
#pragma unroll 1
        for (int e = 0; e < NE; ++e) {
            float p[16];
#pragma unroll
            for (int i = 0; i < 16; ++i) p[i] = 0.f;
#pragma unroll
            for (int j = 0; j < 8; ++j) {
                const int cj = tc * 4 + (j & 3) + ((j >> 2) << 6);
                const float wv2 = w2[(nh0 + cj) * NE + e];
#pragma unroll
                for (int i = 0; i < 16; ++i) p[i] = fmaf(acc[i][j], wv2, p[i]);
            }
#pragma unroll
            for (int i = 0; i < 16; ++i) p[i] = dpp_xor_add<0xB1>(p[i]);
#pragma unroll
            for (int i = 0; i < 16; ++i) p[i] = dpp_xor_add<0x4E>(p[i]);
#pragma unroll
            for (int i = 0; i < 16; ++i) p[i] = swz_xor_add<0x101F>(p[i]);
#pragma unroll
            for (int i = 0; i < 16; ++i) p[i] = swz_xor_add<0x201F>(p[i]);
            if (tc == e) {
#pragma unroll
                for (int i = 0; i < 16; ++i) logits[i] += p[i];
            }
        }
    }

    // ---- gather logits to LDS overlay ----
    const float be = b2[tc];
#pragma unroll
    for (int i = 0; i < 16; ++i)
        l_lds[(tr * 16 + i) * (NE + 1) + tc] = logits[i] + be;
    __syncthreads();

    // ---- per-row top-2 + masked softmax (1 thread per row) ----
    {
        float l[NE];
#pragma unroll
        for (int e = 0; e < NE; ++e) l[e] = l_lds[t * (NE + 1) + e];

        float m1 = -INFINITY; int i1 = 0;
#pragma unroll
        for (int e = 0; e < NE; ++e)
            if (l[e] > m1) { m1 = l[e]; i1 = e; }
        float m2 = -INFINITY; int i2 = -1;
#pragma unroll
        for (int e = 0; e < NE; ++e)
            if (e != i1 && l[e] > m2) { m2 = l[e]; i2 = e; }

        float s[NE];
#pragma unroll
        for (int e = 0; e < NE; ++e)
            s[e] = (e == i1 || e == i2) ? l[e] : 0.f;

        float mx = s[0];
#pragma unroll
        for (int e = 1; e < NE; ++e) mx = fmaxf(mx, s[e]);

        float ex[NE];
        float sum = 0.f;
#pragma unroll
        for (int e = 0; e < NE; ++e) { ex[e] = expf(s[e] - mx); sum += ex[e]; }

        float* og = out + (row0 + t) * NE;
#pragma unroll
        for (int e = 0; e < NE; ++e) og[e] = ex[e] / sum;
    }
}

extern "C" void kernel_launch(void* const* d_in, const int* in_sizes, int n_in,
                              void* d_out, int out_size, void* d_ws, size_t ws_size,
                              hipStream_t stream) {
    const float* x  = (const float*)d_in[0];
    const float* w1 = (const float*)d_in[1];
    const float* b1 = (const float*)d_in[2];
    const float* w2 = (const float*)d_in[3];
    const float* b2 = (const float*)d_in[4];
    float* outp = (float*)d_out;

    dim3 grid(524288 / BM);
    dim3 block(256);
    hipLaunchKernelGGL(moe_router, grid, block, 0, stream,
                       x, w1, b1, w2, b2, outp);
}

// Round 4
// 2054.631 us; speedup vs baseline: 12.9772x; 12.9772x over previous
//
#include <hip/hip_runtime.h>
#include <cmath>

#define BM   256   // rows per block
#define NH   128   // hidden chunk width
#define BK   16    // K slice
#define NE   16
#define DIN  256
#define DHID 512
#define XSTR 256   // x_sl row stride (no pad: writes stride-1, reads broadcast/2-way)
#define WOFF (BK * XSTR)   // w_sl float offset within smem

template<int CTRL>
__device__ __forceinline__ float dpp_xor_add(float v) {
    int s = __builtin_amdgcn_update_dpp(0, __float_as_int(v), CTRL, 0xF, 0xF, true);
    return v + __int_as_float(s);
}
template<int OFF>
__device__ __forceinline__ float swz_xor_add(float v) {
    int s = __builtin_amdgcn_ds_swizzle(__float_as_int(v), OFF);
    return v + __int_as_float(s);
}

__device__ __forceinline__ void load_lds16(const float* g, float* l) {
    __builtin_amdgcn_global_load_lds(
        (const __attribute__((address_space(1))) void*)g,
        (__attribute__((address_space(3))) void*)l,
        16, 0, 0);
}

__global__ __launch_bounds__(256, 2)   // ROUND-4: (256,4) caused full acc spill (129 GB scratch)
void moe_router(const float* __restrict__ x,
                const float* __restrict__ w1,
                const float* __restrict__ b1,
                const float* __restrict__ w2,
                const float* __restrict__ b2,
                float* __restrict__ out)
{
    // x_sl: [BK][XSTR] transposed x slice; w_sl: [BK][NH] linear (global_load_lds dest)
    // epilogue overlay l_lds: [BM][NE+1] = 4352 floats
    __shared__ __align__(16) float smem[BK * XSTR + BK * NH];
    float* x_sl  = smem;
    float* w_sl  = smem + WOFF;
    float* l_lds = smem;

    const int t    = threadIdx.x;
    const int tc   = t & 15;    // column group / owned expert (pinned by reduction tree)
    const int tr   = t >> 4;    // row group (rows tr*16 .. tr*16+15)
    const int lane = t & 63;
    const int wv   = t >> 6;    // wave id 0..3
    const long long row0 = (long long)blockIdx.x * BM;

    float logits[16];
#pragma unroll
    for (int i = 0; i < 16; ++i) logits[i] = 0.f;

    for (int ch = 0; ch < DHID / NH; ++ch) {
        const int nh0 = ch * NH;
        float acc[16][8];
#pragma unroll
        for (int i = 0; i < 16; ++i)
#pragma unroll
            for (int j = 0; j < 8; ++j) acc[i][j] = 0.f;

        for (int ks = 0; ks < DIN / BK; ++ks) {
            const int k0 = ks * BK;

            // ---- stage w1 slice via global_load_lds (wave-uniform LDS base) ----
            {
                const float* s0 = w1 + (long long)(k0 + 4 * wv + (lane >> 5)) * DHID
                                     + nh0 + 4 * (lane & 31);
                load_lds16(s0,             w_sl + 512 * wv + 256 * 0);
                load_lds16(s0 + 2 * DHID,  w_sl + 512 * wv + 256 * 1);
            }
            // ---- stage x slice (transposed): thread t owns row t, 16 k's ----
            {
                const float* xg = x + (row0 + t) * DIN + k0;
#pragma unroll
                for (int u = 0; u < 4; ++u) {
                    float4 v = ((const float4*)xg)[u];
                    const int kk = u * 4;
                    x_sl[(kk + 0) * XSTR + t] = v.x;
                    x_sl[(kk + 1) * XSTR + t] = v.y;
                    x_sl[(kk + 2) * XSTR + t] = v.z;
                    x_sl[(kk + 3) * XSTR + t] = v.w;
                }
            }
            __syncthreads();

            // ---- 256x128x16 fp32 register-tile step: 16x8 per thread ----
#pragma unroll 4
            for (int k = 0; k < BK; ++k) {
                float4 xa = *(const float4*)&x_sl[k * XSTR + tr * 16];
                float4 xb = *(const float4*)&x_sl[k * XSTR + tr * 16 + 4];
                float4 xc = *(const float4*)&x_sl[k * XSTR + tr * 16 + 8];
                float4 xd = *(const float4*)&x_sl[k * XSTR + tr * 16 + 12];
                float4 wa = *(const float4*)&w_sl[k * NH + tc * 4];
                float4 wb = *(const float4*)&w_sl[k * NH + 64 + tc * 4];
                float xr[16] = {xa.x, xa.y, xa.z, xa.w, xb.x, xb.y, xb.z, xb.w,
                                xc.x, xc.y, xc.z, xc.w, xd.x, xd.y, xd.z, xd.w};
                float wc[8]  = {wa.x, wa.y, wa.z, wa.w, wb.x, wb.y, wb.z, wb.w};
#pragma unroll
                for (int i = 0; i < 16; ++i)
#pragma unroll
                    for (int j = 0; j < 8; ++j)
                        acc[i][j] = fmaf(xr[i], wc[j], acc[i][j]);
            }
            __syncthreads();
        }

        // ---- bias + relu ----
#pragma unroll
        for (int j = 0; j < 8; ++j) {
            const int cj = tc * 4 + (j & 3) + ((j >> 2) << 6);
            const float bj = b1[nh0 + cj];
#pragma unroll
            for (int i = 0; i < 16; ++i)
                acc[i][j] = fmaxf(acc[i][j] + bj, 0.f);
        }

        // ---- fused layer 2 (register-only; DPP xor1/xor2 + swizzle xor4/xor8) ----
#pragma unroll 1
        for (int e = 0; e < NE; ++e) {
            float p[16];
#pragma unroll
            for (int i = 0; i < 16; ++i) p[i] = 0.f;
#pragma unroll
            for (int j = 0; j < 8; ++j) {
                const int cj = tc * 4 + (j & 3) + ((j >> 2) << 6);
                const float wv2 = w2[(nh0 + cj) * NE + e];
#pragma unroll
                for (int i = 0; i < 16; ++i) p[i] = fmaf(acc[i][j], wv2, p[i]);
            }
#pragma unroll
            for (int i = 0; i < 16; ++i) p[i] = dpp_xor_add<0xB1>(p[i]);
#pragma unroll
            for (int i = 0; i < 16; ++i) p[i] = dpp_xor_add<0x4E>(p[i]);
#pragma unroll
            for (int i = 0; i < 16; ++i) p[i] = swz_xor_add<0x101F>(p[i]);
#pragma unroll
            for (int i = 0; i < 16; ++i) p[i] = swz_xor_add<0x201F>(p[i]);
            if (tc == e) {
#pragma unroll
                for (int i = 0; i < 16; ++i) logits[i] += p[i];
            }
        }
    }

    // ---- gather logits to LDS overlay ----
    const float be = b2[tc];
#pragma unroll
    for (int i = 0; i < 16; ++i)
        l_lds[(tr * 16 + i) * (NE + 1) + tc] = logits[i] + be;
    __syncthreads();

    // ---- per-row top-2 + masked softmax (1 thread per row) ----
    {
        float l[NE];
#pragma unroll
        for (int e = 0; e < NE; ++e) l[e] = l_lds[t * (NE + 1) + e];

        float m1 = -INFINITY; int i1 = 0;
#pragma unroll
        for (int e = 0; e < NE; ++e)
            if (l[e] > m1) { m1 = l[e]; i1 = e; }
        float m2 = -INFINITY; int i2 = -1;
#pragma unroll
        for (int e = 0; e < NE; ++e)
            if (e != i1 && l[e] > m2) { m2 = l[e]; i2 = e; }

        float s[NE];
#pragma unroll
        for (int e = 0; e < NE; ++e)
            s[e] = (e == i1 || e == i2) ? l[e] : 0.f;

        float mx = s[0];
#pragma unroll
        for (int e = 1; e < NE; ++e) mx = fmaxf(mx, s[e]);

        float ex[NE];
        float sum = 0.f;
#pragma unroll
        for (int e = 0; e < NE; ++e) { ex[e] = expf(s[e] - mx); sum += ex[e]; }

        float* og = out + (row0 + t) * NE;
#pragma unroll
        for (int e = 0; e < NE; ++e) og[e] = ex[e] / sum;
    }
}

extern "C" void kernel_launch(void* const* d_in, const int* in_sizes, int n_in,
                              void* d_out, int out_size, void* d_ws, size_t ws_size,
                              hipStream_t stream) {
    const float* x  = (const float*)d_in[0];
    const float* w1 = (const float*)d_in[1];
    const float* b1 = (const float*)d_in[2];
    const float* w2 = (const float*)d_in[3];
    const float* b2 = (const float*)d_in[4];
    float* outp = (float*)d_out;

    dim3 grid(524288 / BM);
    dim3 block(256);
    hipLaunchKernelGGL(moe_router, grid, block, 0, stream,
                       x, w1, b1, w2, b2, outp);
}

// Round 5
// 1346.964 us; speedup vs baseline: 19.7951x; 1.5254x over previous
//
#include <hip/hip_runtime.h>
#include <cmath>

#define NE   16
#define DIN  256
#define DHID 512
#define NROW 524288
#define TAU  4e-4f

typedef __bf16 bf16;
typedef bf16  bf16x8 __attribute__((ext_vector_type(8)));
typedef float f32x4  __attribute__((ext_vector_type(4)));

template<int CTRL>
__device__ __forceinline__ float dpp_xor_add(float v) {
    int s = __builtin_amdgcn_update_dpp(0, __float_as_int(v), CTRL, 0xF, 0xF, true);
    return v + __int_as_float(s);
}
template<int OFF>
__device__ __forceinline__ float swz_xor_add(float v) {
    int s = __builtin_amdgcn_ds_swizzle(__float_as_int(v), OFF);
    return v + __int_as_float(s);
}

// ---------------- K0: split w1 -> bf16 hi/lo, transposed [col][k] ----------------
__global__ __launch_bounds__(256)
void split_w1_k(const float* __restrict__ w1, bf16* __restrict__ t_hi,
                bf16* __restrict__ t_lo) {
    int i = blockIdx.x * 256 + threadIdx.x;      // 131072 elems
    int col = i & 511, k = i >> 9;
    float v = w1[k * DHID + col];                // coalesced read
    bf16 h = (bf16)v;
    t_hi[col * DIN + k] = h;
    t_lo[col * DIN + k] = (bf16)(v - (float)h);
}

// ---------------- Pass A: MFMA bf16x3 router + gap flagging ----------------
__global__ __launch_bounds__(256, 2)
void router_mfma_k(const float* __restrict__ x,
                   const float* __restrict__ b1,
                   const float* __restrict__ w2,
                   const float* __restrict__ b2,
                   float* __restrict__ out,
                   const bf16* __restrict__ w1t_hi,
                   const bf16* __restrict__ w1t_lo,
                   unsigned* __restrict__ cnt,
                   unsigned* __restrict__ ids,
                   unsigned cap)
{
    // [g=kblock][row/col (pad 129)][8 bf16]; pad de-aliases g-planes (+4 banks)
    __shared__ __align__(16) bf16 xh_s[4][129][8];
    __shared__ __align__(16) bf16 xl_s[4][129][8];
    __shared__ __align__(16) bf16 wh_s[4][129][8];
    __shared__ __align__(16) bf16 wl_s[4][129][8];
    __shared__ float l_lds[128][NE + 1];

    const int t    = threadIdx.x;
    const int lane = t & 63;
    const int wv   = t >> 6;        // wave 0..3, owns rows [32wv, 32wv+32)
    const int c    = lane & 15;     // A-row / B-col / C-col lane coord; owned expert
    const int g    = lane >> 4;     // k-block coord; C row-group
    const long long row0 = (long long)blockIdx.x * 128;

    float lg[8];
#pragma unroll
    for (int i = 0; i < 8; ++i) lg[i] = 0.f;

    for (int ch = 0; ch < 4; ++ch) {
        const int nh0 = ch * 128;
        f32x4 acc[2][8];
#pragma unroll
        for (int ti = 0; ti < 2; ++ti)
#pragma unroll
            for (int tj = 0; tj < 8; ++tj)
#pragma unroll
                for (int r = 0; r < 4; ++r) acc[ti][tj][r] = 0.f;

        for (int ks = 0; ks < 8; ++ks) {
            const int k0 = ks * 32;
            __syncthreads();
            // ---- stage x slice: 128 rows x 32 k, split hi/lo ----
#pragma unroll
            for (int u = 0; u < 4; ++u) {
                int idx = u * 256 + t;
                int row = idx >> 3, f4 = idx & 7;
                float4 v = *(const float4*)(x + (row0 + row) * DIN + k0 + f4 * 4);
                int gg = f4 >> 1, j0 = (f4 & 1) * 4;
                bf16* dh = &xh_s[gg][row][j0];
                bf16* dl = &xl_s[gg][row][j0];
                float vv[4] = {v.x, v.y, v.z, v.w};
#pragma unroll
                for (int q = 0; q < 4; ++q) {
                    bf16 hb = (bf16)vv[q];
                    dh[q] = hb;
                    dl[q] = (bf16)(vv[q] - (float)hb);
                }
            }
            // ---- stage w slice from pre-split ws: 128 cols x 32 k ----
            {
                int col = t >> 1, half = t & 1;
                const bf16* sh = w1t_hi + (nh0 + col) * DIN + k0 + 16 * half;
                const bf16* sl = w1t_lo + (nh0 + col) * DIN + k0 + 16 * half;
#pragma unroll
                for (int u = 0; u < 2; ++u) {
                    *(bf16x8*)&wh_s[2 * half + u][col][0] = *(const bf16x8*)(sh + 8 * u);
                    *(bf16x8*)&wl_s[2 * half + u][col][0] = *(const bf16x8*)(sl + 8 * u);
                }
            }
            __syncthreads();
            // ---- MFMA: 2(ti) x 8(tj) tiles, bf16x3 (hh, hl, lh) ----
            bf16x8 ah[2], al[2];
#pragma unroll
            for (int ti = 0; ti < 2; ++ti) {
                ah[ti] = *(const bf16x8*)&xh_s[g][32 * wv + 16 * ti + c][0];
                al[ti] = *(const bf16x8*)&xl_s[g][32 * wv + 16 * ti + c][0];
            }
#pragma unroll
            for (int tj = 0; tj < 8; ++tj) {
                bf16x8 bh = *(const bf16x8*)&wh_s[g][16 * tj + c][0];
                bf16x8 bl = *(const bf16x8*)&wl_s[g][16 * tj + c][0];
#pragma unroll
                for (int ti = 0; ti < 2; ++ti) {
                    acc[ti][tj] = __builtin_amdgcn_mfma_f32_16x16x32_bf16(ah[ti], bh, acc[ti][tj], 0, 0, 0);
                    acc[ti][tj] = __builtin_amdgcn_mfma_f32_16x16x32_bf16(ah[ti], bl, acc[ti][tj], 0, 0, 0);
                    acc[ti][tj] = __builtin_amdgcn_mfma_f32_16x16x32_bf16(al[ti], bh, acc[ti][tj], 0, 0, 0);
                }
            }
        }

        // ---- bias + relu (C/D: col = 16tj + c, row = 32wv + 16ti + 4g + r) ----
#pragma unroll
        for (int tj = 0; tj < 8; ++tj) {
            float bj = b1[nh0 + 16 * tj + c];
#pragma unroll
            for (int ti = 0; ti < 2; ++ti)
#pragma unroll
                for (int r = 0; r < 4; ++r)
                    acc[ti][tj][r] = fmaxf(acc[ti][tj][r] + bj, 0.f);
        }

        // ---- fused layer 2 (fp32 VALU) ----
#pragma unroll 1
        for (int e = 0; e < NE; ++e) {
            float p[8];
#pragma unroll
            for (int i = 0; i < 8; ++i) p[i] = 0.f;
#pragma unroll
            for (int tj = 0; tj < 8; ++tj) {
                float wvv = w2[(nh0 + 16 * tj + c) * NE + e];
#pragma unroll
                for (int ti = 0; ti < 2; ++ti)
#pragma unroll
                    for (int r = 0; r < 4; ++r)
                        p[ti * 4 + r] = fmaf(acc[ti][tj][r], wvv, p[ti * 4 + r]);
            }
#pragma unroll
            for (int i = 0; i < 8; ++i) p[i] = dpp_xor_add<0xB1>(p[i]);
#pragma unroll
            for (int i = 0; i < 8; ++i) p[i] = dpp_xor_add<0x4E>(p[i]);
#pragma unroll
            for (int i = 0; i < 8; ++i) p[i] = swz_xor_add<0x101F>(p[i]);
#pragma unroll
            for (int i = 0; i < 8; ++i) p[i] = swz_xor_add<0x201F>(p[i]);
            if (c == e) {
#pragma unroll
                for (int i = 0; i < 8; ++i) lg[i] += p[i];
            }
        }
    }

    __syncthreads();
    {
        float b2c = b2[c];
#pragma unroll
        for (int ti = 0; ti < 2; ++ti)
#pragma unroll
            for (int r = 0; r < 4; ++r)
                l_lds[32 * wv + 16 * ti + 4 * g + r][c] = lg[ti * 4 + r] + b2c;
    }
    __syncthreads();

    if (t < 128) {
        float l[NE];
#pragma unroll
        for (int e = 0; e < NE; ++e) l[e] = l_lds[t][e];

        float m1 = -INFINITY; int i1 = 0;
#pragma unroll
        for (int e = 0; e < NE; ++e)
            if (l[e] > m1) { m1 = l[e]; i1 = e; }
        float m2 = -INFINITY; int i2 = -1;
#pragma unroll
        for (int e = 0; e < NE; ++e)
            if (e != i1 && l[e] > m2) { m2 = l[e]; i2 = e; }
        float m3 = -INFINITY;
#pragma unroll
        for (int e = 0; e < NE; ++e)
            if (e != i1 && e != i2 && l[e] > m3) m3 = l[e];

        if (m2 - m3 < TAU) {           // borderline 2/3 gap -> exact fixup
            unsigned idx = atomicAdd(cnt, 1u);
            if (idx < cap) ids[idx] = (unsigned)(row0 + t);
        }

        float s[NE];
#pragma unroll
        for (int e = 0; e < NE; ++e)
            s[e] = (e == i1 || e == i2) ? l[e] : 0.f;
        float mx = s[0];
#pragma unroll
        for (int e = 1; e < NE; ++e) mx = fmaxf(mx, s[e]);
        float ex[NE];
        float sum = 0.f;
#pragma unroll
        for (int e = 0; e < NE; ++e) { ex[e] = expf(s[e] - mx); sum += ex[e]; }
        float* og = out + (row0 + t) * NE;
#pragma unroll
        for (int e = 0; e < NE; ++e) og[e] = ex[e] / sum;
    }
}

// ---------------- Pass B: bit-exact (round-2 order) recompute of flagged rows ----------------
__global__ __launch_bounds__(256)
void fixup_k(const float* __restrict__ x,
             const float* __restrict__ w1,
             const float* __restrict__ b1,
             const float* __restrict__ w2,
             const float* __restrict__ b2,
             float* __restrict__ out,
             const unsigned* __restrict__ cntp,
             const unsigned* __restrict__ ids,
             unsigned cap)
{
    const int lane = threadIdx.x & 63;
    const int gw   = (int)((blockIdx.x * 256 + threadIdx.x) >> 6);
    const int nw   = (int)((gridDim.x * 256) >> 6);
    unsigned n = *cntp; if (n > cap) n = cap;
    const int c = lane & 15;      // plays round-2's tc
    const int g = lane >> 4;      // chunk index 0..3

    for (unsigned wi = gw; wi < n; wi += nw) {
        unsigned row = ids[wi];
        const float* xr = x + (size_t)row * DIN;
        const int nh0 = 128 * g;
        int cols[8];
#pragma unroll
        for (int j = 0; j < 8; ++j)
            cols[j] = nh0 + c * 4 + (j & 3) + ((j >> 2) << 6);

        // h chains: k ascending 0..255, one fmaf per k  (== rounds 1/2/4 order)
        float a[8];
#pragma unroll
        for (int j = 0; j < 8; ++j) a[j] = 0.f;
        for (int k4 = 0; k4 < 64; ++k4) {
            float4 xv = *(const float4*)(xr + k4 * 4);   // uniform addr: broadcast
            const float* wp = w1 + (size_t)(k4 * 4) * DHID;
#pragma unroll
            for (int j = 0; j < 8; ++j) {
                a[j] = fmaf(xv.x, wp[cols[j]],            a[j]);
                a[j] = fmaf(xv.y, wp[DHID + cols[j]],     a[j]);
                a[j] = fmaf(xv.z, wp[2 * DHID + cols[j]], a[j]);
                a[j] = fmaf(xv.w, wp[3 * DHID + cols[j]], a[j]);
            }
        }
        float h[8];
#pragma unroll
        for (int j = 0; j < 8; ++j) h[j] = fmaxf(a[j] + b1[cols[j]], 0.f);

        float l[NE];
#pragma unroll 1
        for (int e = 0; e < NE; ++e) {
            float p = 0.f;
#pragma unroll
            for (int j = 0; j < 8; ++j)
                p = fmaf(h[j], w2[cols[j] * NE + e], p);
            // same xor-tree as round-2 (values identical to dpp/swizzle path)
            p += __shfl_xor(p, 1, 64);
            p += __shfl_xor(p, 2, 64);
            p += __shfl_xor(p, 4, 64);
            p += __shfl_xor(p, 8, 64);
            // round-2 keeps lane tc==e's tree; chunk chain T0..T3 left-assoc
            float t0 = __shfl(p, 0 * 16 + e, 64);
            float t1 = __shfl(p, 1 * 16 + e, 64);
            float t2 = __shfl(p, 2 * 16 + e, 64);
            float t3 = __shfl(p, 3 * 16 + e, 64);
            l[e] = (((t0 + t1) + t2) + t3) + b2[e];
        }

        if (lane == 0) {   // exact round-2 epilogue
            float m1 = -INFINITY; int i1 = 0;
#pragma unroll
            for (int e = 0; e < NE; ++e)
                if (l[e] > m1) { m1 = l[e]; i1 = e; }
            float m2 = -INFINITY; int i2 = -1;
#pragma unroll
            for (int e = 0; e < NE; ++e)
                if (e != i1 && l[e] > m2) { m2 = l[e]; i2 = e; }
            float s[NE];
#pragma unroll
            for (int e = 0; e < NE; ++e)
                s[e] = (e == i1 || e == i2) ? l[e] : 0.f;
            float mx = s[0];
#pragma unroll
            for (int e = 1; e < NE; ++e) mx = fmaxf(mx, s[e]);
            float ex[NE];
            float sum = 0.f;
#pragma unroll
            for (int e = 0; e < NE; ++e) { ex[e] = expf(s[e] - mx); sum += ex[e]; }
            float* og = out + (size_t)row * NE;
#pragma unroll
            for (int e = 0; e < NE; ++e) og[e] = ex[e] / sum;
        }
    }
}

extern "C" void kernel_launch(void* const* d_in, const int* in_sizes, int n_in,
                              void* d_out, int out_size, void* d_ws, size_t ws_size,
                              hipStream_t stream) {
    const float* x  = (const float*)d_in[0];
    const float* w1 = (const float*)d_in[1];
    const float* b1 = (const float*)d_in[2];
    const float* w2 = (const float*)d_in[3];
    const float* b2 = (const float*)d_in[4];
    float* outp = (float*)d_out;

    // ws layout: [0, 256K): w1t_hi | [256K, 512K): w1t_lo | [1M): u32 counter | [1M+64): ids
    bf16*     w1t_hi = (bf16*)d_ws;
    bf16*     w1t_lo = (bf16*)((char*)d_ws + (256u << 10));
    unsigned* cnt    = (unsigned*)((char*)d_ws + (1u << 20));
    unsigned* ids    = (unsigned*)((char*)d_ws + (1u << 20) + 64);
    unsigned  cap    = 0;
    if (ws_size > (1u << 20) + 64)
        cap = (unsigned)((ws_size - (1u << 20) - 64) / 4);

    hipMemsetAsync((char*)d_ws + (1u << 20), 0, 4, stream);
    split_w1_k<<<dim3(512), dim3(256), 0, stream>>>(w1, w1t_hi, w1t_lo);
    router_mfma_k<<<dim3(NROW / 128), dim3(256), 0, stream>>>(
        x, b1, w2, b2, outp, w1t_hi, w1t_lo, cnt, ids, cap);
    fixup_k<<<dim3(256), dim3(256), 0, stream>>>(
        x, w1, b1, w2, b2, outp, cnt, ids, cap);
}